// Round 9
// baseline (1435.059 us; speedup 1.0000x reference)
//
#include <hip/hip_runtime.h>

#define T_ 512
#define B_ 256
#define H_ 256
#define DIN_ 64

typedef __attribute__((ext_vector_type(8))) short short8;
typedef __attribute__((ext_vector_type(4))) float f32x4;
typedef __attribute__((ext_vector_type(4))) unsigned int u32x4;

__device__ __forceinline__ unsigned short f2bf(float f) {
  unsigned u = __float_as_uint(f);
  u += 0x7FFFu + ((u >> 16) & 1u);   // RNE
  return (unsigned short)(u >> 16);
}
__device__ __forceinline__ float bf2f(unsigned short s) {
  return __uint_as_float(((unsigned)s) << 16);
}
__device__ __forceinline__ float sigm(float x) { return 1.0f / (1.0f + __expf(-x)); }
__device__ __forceinline__ float tanh_(float x) {
  float xx = fminf(fmaxf(x, -30.0f), 30.0f);
  float e = __expf(2.0f * xx);
  return (e - 1.0f) / (e + 1.0f);
}

// Split poll: ISSUE the sc1 load early (fire), WAIT later -- the LLC RT
// overlaps the local-K MFMA phase between the two. sc1 = proven agent-scope
// class (R0-R7). "=&v" early-clobber: result can never alias the addr pair.
__device__ __forceinline__ void poll_issue(const unsigned* p, u32x4& a) {
  asm volatile("global_load_dwordx4 %0, %1, off sc1"
               : "=&v"(a) : "v"(p) : "memory");
}
__device__ __forceinline__ void poll_wait(u32x4& a) {
  asm volatile("s_waitcnt vmcnt(0)" : "+v"(a) :: "memory");
}
__device__ __forceinline__ void load4_sc1(const unsigned* p, u32x4& a) {
  asm volatile("global_load_dwordx4 %0, %1, off sc1\n\t"
               "s_waitcnt vmcnt(0)"
               : "=&v"(a) : "v"(p) : "memory");
}
__device__ __forceinline__ bool tags_ok1(u32x4 a, unsigned w) {
  unsigned m = (a.x >> 16) ^ w; m |= (a.y >> 16) ^ w;
  m |= (a.z >> 16) ^ w;         m |= (a.w >> 16) ^ w;
  return m == 0;
}

// Grid: 32 wgs x 512 threads (8 waves). wgid = half*16 + gb.
//   gb: batch group (16 rows).  half: h-col half (128 cols, base ob=half*128).
// Exchange group = 2 wgs {gb, gb+16} (same mod-16 -> same XCD under round
// robin; perf-only). Each wg computes the 4 gates for its OWN 128 cols,
// needing full h^{s-1}: own half lives in LDS (written by own cell phase),
// peer half arrives via the proven tagged-parity sc1 exchange.
//
// K-split schedule (the latency lever): gates K = 320 = x(64) + own-h(128)
// + peer-h(128). Per step: issue poll -> MFMA x+own chunks (~60% of K, no
// peer data) -> wait/check poll (RT overlapped) -> barrier B -> MFMA peer
// chunks -> gbuf -> barrier C -> cell (4 cells/thread) -> publish own half
// (tagged sc1 atomic stores) -> restage x -> barrier D.
//
// Per-wave compute = R0 composite: wave wv -> gate g=wv&3, quarter q=wv>>2,
// 4 col-tiles (cb=q*4+jt) of ONE gate, A-frag shared across the 4 B-chains
// (m93-verified GEMM idiom); gbuf -> separate cell threads (NOT the
// quarantined R1-R3 in-reg-cell remap).
// W slot order: bhw[jt][k] holds h-chunk (half*4+k)&7 -> slots 0..3 = own
// chunks, 4..7 = peer chunks; ALL register-array indices compile-time.
//
// Protocol safety: identical tagged-parity invariant as R0 (group-size-
// agnostic; R5's group-4 variant passed): publish(s) happens only after
// acquiring ALL of s-1 (barrier-ordered), peer published s-1 only after
// consuming my s-2 -> my publish(s) clobber of my s-2 entry is safe.
// ws poisoned 0xAA/launch -> tag 0xAAAA never matches (want in [1,512]).
__global__ __launch_bounds__(512, 2) void lstm_kern(
    const float* __restrict__ xin, const float* __restrict__ h0f,
    const float* __restrict__ c0f, const float* __restrict__ Wih,
    const float* __restrict__ Whh, const float* __restrict__ bias,
    const float* __restrict__ Wout, const float* __restrict__ bout,
    float* __restrict__ out, unsigned* hbuf32)
{
  const int tid  = threadIdx.x;
  const int gb   = blockIdx.x & 15;   // batch group (16 rows)
  const int half = blockIdx.x >> 4;   // h-col half
  const int ob   = half * 128;        // own col base
  const int pb   = 128 - ob;          // peer col base
  const int wv   = tid >> 6;          // 8 waves
  const int ln   = tid & 63;
  const int g    = wv & 3;            // gate (i,f,g,o)
  const int q    = wv >> 2;           // col quarter within own half
  const int colB = ln & 15;           // MFMA n (B) / m (A) lane index
  const int krow = ln >> 4;           // MFMA k-quad

  __shared__ unsigned short h_s[16 * 264];  // full h (both halves), pitch 264
  __shared__ unsigned short x_s[16 * 72];
  __shared__ float gbuf[4 * 16 * 132];      // [gate][row][128 own cols + pad]

  // ---- W fragments: 4 tiles of gate g over own cols (B-operand layout) ----
  short8 bhw[4][8], bxw[4][2];
  float bvw[4];
  #pragma unroll
  for (int jt = 0; jt < 4; ++jt) {
    const int jr = g * H_ + ob + (q * 4 + jt) * 16 + colB;   // row in [0,4H)
    #pragma unroll
    for (int k = 0; k < 8; ++k) {
      const int kcm = (half * 4 + k) & 7;   // slot k <-> h-chunk kcm
      const float* p = Whh + jr * H_ + kcm * 32 + krow * 8;
      short8 f;
      #pragma unroll
      for (int i = 0; i < 8; ++i) f[i] = (short)f2bf(p[i]);
      bhw[jt][k] = f;
    }
    #pragma unroll
    for (int kc = 0; kc < 2; ++kc) {
      const float* p = Wih + jr * DIN_ + kc * 32 + krow * 8;
      short8 f;
      #pragma unroll
      for (int i = 0; i < 8; ++i) f[i] = (short)f2bf(p[i]);
      bxw[jt][kc] = f;
    }
    bvw[jt] = bias[jr];
  }

  // ---- cell mapping: thread owns (row crow, own cols gcol..gcol+3) ----
  const int crow = tid >> 5;            // 0..15
  const int cl4  = (tid & 31) * 4;      // 0..124
  const int grow = gb * 16 + crow;
  const int gcol = ob + cl4;
  float c_val[4], h_val[4];
  #pragma unroll
  for (int i = 0; i < 4; ++i) {
    c_val[i] = c0f[grow * H_ + gcol + i];
    h_val[i] = 0.0f;
  }

  // ---- x staging: 2 floats/thread/step, prefetched one step ahead ----
  const int xr = tid >> 5, xc = (tid & 31) * 2;
  const float* xrow = xin + (gb * 16 + xr) * (T_ * DIN_) + xc;
  {
    float2 v = *(const float2*)(xrow);            // x[t=0]
    x_s[xr * 72 + xc]     = f2bf(v.x);
    x_s[xr * 72 + xc + 1] = f2bf(v.y);
  }
  float2 xcur = *(const float2*)(xrow + DIN_);    // prefetch x[t=1]

  // ---- stage full h0 (both halves) ----
  {
    const int r = tid >> 5, c8 = (tid & 31) * 8;
    float4 v0 = *(const float4*)(h0f + (gb * 16 + r) * H_ + c8);
    float4 v1 = *(const float4*)(h0f + (gb * 16 + r) * H_ + c8 + 4);
    unsigned short* qq = &h_s[r * 264 + c8];
    qq[0] = f2bf(v0.x); qq[1] = f2bf(v0.y); qq[2] = f2bf(v0.z); qq[3] = f2bf(v0.w);
    qq[4] = f2bf(v1.x); qq[5] = f2bf(v1.y); qq[6] = f2bf(v1.z); qq[7] = f2bf(v1.w);
  }

  // hbuf32[2 parity][16 gb][16 rows][256 cols] dwords
  const int pr = tid >> 5, pc = pb + (tid & 31) * 4;   // poll target (peer)
  const unsigned* ldp_base = hbuf32 + gb * 4096 + pr * 256 + pc;
  unsigned* stp_base = hbuf32 + gb * 4096 + crow * 256 + gcol;

  __syncthreads();

  for (int s = 1; s <= T_; ++s) {
    u32x4 pv;
    const unsigned* ldp = ldp_base + (((s - 1) & 1) << 16);
    if (s > 1) poll_issue(ldp, pv);   // fire; RT overlaps local MFMA below

    // ---- phase 1: x-chunks + OWN-half h-chunks (no peer data) ----
    f32x4 acc[4] = {{0.f,0.f,0.f,0.f},{0.f,0.f,0.f,0.f},
                    {0.f,0.f,0.f,0.f},{0.f,0.f,0.f,0.f}};
    #pragma unroll
    for (int kc = 0; kc < 2; ++kc) {
      short8 a = *(const short8*)&x_s[colB * 72 + kc * 32 + krow * 8];
      #pragma unroll
      for (int jt = 0; jt < 4; ++jt)
        acc[jt] = __builtin_amdgcn_mfma_f32_16x16x32_bf16(a, bxw[jt][kc], acc[jt], 0, 0, 0);
    }
    #pragma unroll
    for (int k = 0; k < 4; ++k) {     // own chunks: slots 0..3
      const int kcm = half * 4 + k;
      short8 a = *(const short8*)&h_s[colB * 264 + kcm * 32 + krow * 8];
      #pragma unroll
      for (int jt = 0; jt < 4; ++jt)
        acc[jt] = __builtin_amdgcn_mfma_f32_16x16x32_bf16(a, bhw[jt][k], acc[jt], 0, 0, 0);
    }

    // ---- complete poll of peer half h^{s-1} ----
    if (s > 1) {
      const unsigned want = (unsigned)(s - 1);
      poll_wait(pv);
      if (!tags_ok1(pv, want)) {
        int tries = 0;
        do {
          load4_sc1(ldp, pv);
          if (tags_ok1(pv, want)) break;
        } while (++tries < (1 << 18));   // hang guard (unreachable)
      }
      unsigned* q32 = (unsigned*)&h_s[pr * 264 + pc];
      q32[0] = (pv.x & 0xFFFFu) | (pv.y << 16);
      q32[1] = (pv.z & 0xFFFFu) | (pv.w << 16);
    }
    __syncthreads();   // (B) peer half staged

    // ---- phase 2: PEER-half h-chunks ----
    #pragma unroll
    for (int k = 4; k < 8; ++k) {     // peer chunks: slots 4..7
      const int kcm = (half * 4 + k) & 7;
      short8 a = *(const short8*)&h_s[colB * 264 + kcm * 32 + krow * 8];
      #pragma unroll
      for (int jt = 0; jt < 4; ++jt)
        acc[jt] = __builtin_amdgcn_mfma_f32_16x16x32_bf16(a, bhw[jt][k], acc[jt], 0, 0, 0);
    }
    #pragma unroll
    for (int jt = 0; jt < 4; ++jt) {
      const int gc0 = (q * 4 + jt) * 16 + colB;
      #pragma unroll
      for (int i = 0; i < 4; ++i)   // D layout: col=lane&15, row=krow*4+i
        gbuf[g * 2112 + (krow * 4 + i) * 132 + gc0] = acc[jt][i] + bvw[jt];
    }
    __syncthreads();   // (C) gates staged

    // ---- cell: 4 cells/thread; publish own half; write own h_s ----
    {
      const f32x4 vi = *(const f32x4*)&gbuf[0 * 2112 + crow * 132 + cl4];
      const f32x4 vf = *(const f32x4*)&gbuf[1 * 2112 + crow * 132 + cl4];
      const f32x4 vg = *(const f32x4*)&gbuf[2 * 2112 + crow * 132 + cl4];
      const f32x4 vo = *(const f32x4*)&gbuf[3 * 2112 + crow * 132 + cl4];
      unsigned short* hq = &h_s[crow * 264 + gcol];
      unsigned* st = stp_base + ((s & 1) << 16);
      #pragma unroll
      for (int i = 0; i < 4; ++i) {
        c_val[i] = sigm(vf[i]) * c_val[i] + sigm(vi[i]) * tanh_(vg[i]);
        h_val[i] = sigm(vo[i]) * tanh_(c_val[i]);
        unsigned short hb = f2bf(h_val[i]);
        hq[i] = hb;
        __hip_atomic_store(st + i, ((unsigned)s << 16) | (unsigned)hb,
                           __ATOMIC_RELAXED, __HIP_MEMORY_SCOPE_AGENT);
      }
    }
    // restage x for step s+1 (xcur == x[s]); prefetch next
    x_s[xr * 72 + xc]     = f2bf(xcur.x);
    x_s[xr * 72 + xc + 1] = f2bf(xcur.y);
    {
      const int tn = (s + 1 < T_) ? (s + 1) : (T_ - 1);
      xcur = *(const float2*)(xrow + tn * DIN_);
    }
    __syncthreads();   // (D) h_s own + x_s ready for step s+1
  }

  // ---- outputs: rnn_outputs | logits | h | c ----
  #pragma unroll
  for (int i = 0; i < 4; ++i) {
    out[grow * H_ + gcol + i]          = h_val[i];   // out0: rnn_outputs
    out[67584 + grow * H_ + gcol + i]  = h_val[i];   // out2: h (65536+2048)
    out[133120 + grow * H_ + gcol + i] = c_val[i];   // out3: c
  }

  // ---- tail: acquire peer h^T, then logits (half==0 writes) ----
  {
    const unsigned want = (unsigned)T_;
    const unsigned* ldp = ldp_base + ((T_ & 1) << 16);
    u32x4 pv;
    int tries = 0;
    do {
      load4_sc1(ldp, pv);
      if (tags_ok1(pv, want)) break;
    } while (++tries < (1 << 18));
    unsigned* q32 = (unsigned*)&h_s[pr * 264 + pc];
    q32[0] = (pv.x & 0xFFFFu) | (pv.y << 16);
    q32[1] = (pv.z & 0xFFFFu) | (pv.w << 16);
    __syncthreads();
    if (half == 0 && tid < 128) {
      int r = tid >> 3, o = tid & 7;
      float a = bout[o];
      for (int k = 0; k < H_; ++k)
        a = fmaf(bf2f(h_s[r * 264 + k]), Wout[o * H_ + k], a);
      out[65536 + (gb * 16 + r) * 8 + o] = a;        // out1: logits
    }
  }
}

extern "C" void kernel_launch(void* const* d_in, const int* in_sizes, int n_in,
                              void* d_out, int out_size, void* d_ws, size_t ws_size,
                              hipStream_t stream) {
  const float* xin  = (const float*)d_in[0];
  const float* h0f  = (const float*)d_in[1];
  const float* c0f  = (const float*)d_in[2];
  const float* Wih  = (const float*)d_in[3];
  const float* Whh  = (const float*)d_in[4];
  const float* bias = (const float*)d_in[5];
  const float* Wout = (const float*)d_in[6];
  const float* bout = (const float*)d_in[7];
  float* out = (float*)d_out;

  // ws: hbuf32[2][16][16][256] dwords (512 KiB)
  unsigned* hbuf32 = (unsigned*)d_ws;

  void* args[] = {&xin, &h0f, &c0f, &Wih, &Whh, &bias, &Wout, &bout,
                  &out, &hbuf32};
  hipLaunchCooperativeKernel((void*)lstm_kern, dim3(32), dim3(512),
                             args, 0, stream);
}

// Round 10
// 1429.864 us; speedup vs baseline: 1.0036x; 1.0036x over previous
//
#include <hip/hip_runtime.h>

#define T_ 512
#define B_ 256
#define H_ 256
#define DIN_ 64

typedef __attribute__((ext_vector_type(8))) short short8;
typedef __attribute__((ext_vector_type(4))) float f32x4;
typedef __attribute__((ext_vector_type(4))) unsigned int u32x4;

__device__ __forceinline__ unsigned short f2bf(float f) {
  unsigned u = __float_as_uint(f);
  u += 0x7FFFu + ((u >> 16) & 1u);   // RNE
  return (unsigned short)(u >> 16);
}
__device__ __forceinline__ float bf2f(unsigned short s) {
  return __uint_as_float(((unsigned)s) << 16);
}
__device__ __forceinline__ float sigm(float x) { return 1.0f / (1.0f + __expf(-x)); }
__device__ __forceinline__ float tanh_(float x) {
  float xx = fminf(fmaxf(x, -30.0f), 30.0f);
  float e = __expf(2.0f * xx);
  return (e - 1.0f) / (e + 1.0f);
}

// Split poll: ISSUE the sc1 load early (fire), WAIT later -- the LLC RT
// overlaps the local-K MFMA phase between the two. sc1 = proven agent-scope
// class (R0-R7). "=&v" early-clobber: result can never alias the addr pair.
__device__ __forceinline__ void poll_issue(const unsigned* p, u32x4& a) {
  asm volatile("global_load_dwordx4 %0, %1, off sc1"
               : "=&v"(a) : "v"(p) : "memory");
}
__device__ __forceinline__ void poll_wait(u32x4& a) {
  asm volatile("s_waitcnt vmcnt(0)" : "+v"(a) :: "memory");
}
__device__ __forceinline__ void load4_sc1(const unsigned* p, u32x4& a) {
  asm volatile("global_load_dwordx4 %0, %1, off sc1\n\t"
               "s_waitcnt vmcnt(0)"
               : "=&v"(a) : "v"(p) : "memory");
}
__device__ __forceinline__ bool tags_ok1(u32x4 a, unsigned w) {
  unsigned m = (a.x >> 16) ^ w; m |= (a.y >> 16) ^ w;
  m |= (a.z >> 16) ^ w;         m |= (a.w >> 16) ^ w;
  return m == 0;
}

// Grid: 32 wgs x 512 threads (8 waves). wgid = half*16 + gb.
//   gb: batch group (16 rows).  half: h-col half (128 cols, base ob=half*128).
// Exchange group = 2 wgs {gb, gb+16}. Each wg computes the 4 gates for its
// OWN 128 cols; own half of h^{s-1} lives in LDS (written by own cell
// phase), peer half arrives via the proven tagged-parity sc1 exchange.
//
// R10 = R9 (passed, but VGPR-capped at 128 -> W spilled to scratch,
// WRITE_SIZE 132->531MB) with ONE fix: occupancy attributes pin 2 waves/EU
// -> 256 VGPR cap -> W fragments (160 VGPR) stay register-resident.
// __launch_bounds__(512,2) was honored as 2 blocks/CU (128 cap) -- replaced
// by amdgpu_flat_work_group_size + amdgpu_waves_per_eu(2).
//
// K-split schedule (the latency lever): gates K = 320 = x(64) + own-h(128)
// + peer-h(128). Per step: issue poll -> MFMA x+own chunks (~60% of K, no
// peer data) -> wait/check poll (RT overlapped) -> barrier B -> MFMA peer
// chunks -> gbuf -> barrier C -> cell (4 cells/thread) -> publish own half
// (tagged sc1 atomic stores) -> restage x -> barrier D.
//
// Per-wave compute = R0 composite: wave wv -> gate g=wv&3, quarter q=wv>>2,
// 4 col-tiles of ONE gate, A-frag shared across the 4 B-chains (m93 GEMM
// idiom); gbuf -> separate cell threads (NOT the quarantined in-reg remap).
// W slot order: bhw[jt][k] holds h-chunk (half*4+k)&7 -> slots 0..3 = own
// chunks, 4..7 = peer chunks; ALL register-array indices compile-time.
//
// Protocol safety: identical tagged-parity invariant as R0 (group-size-
// agnostic; R5 group-4 and R9 group-2 both passed): publish(s) only after
// acquiring ALL of s-1 (barrier-ordered); peer published s-1 only after
// consuming my s-2 -> my publish(s) clobber of my s-2 entry is safe.
// ws poisoned 0xAA/launch -> tag 0xAAAA never matches (want in [1,512]).
__global__ __attribute__((amdgpu_flat_work_group_size(512, 512),
                          amdgpu_waves_per_eu(2, 2)))
void lstm_kern(
    const float* __restrict__ xin, const float* __restrict__ h0f,
    const float* __restrict__ c0f, const float* __restrict__ Wih,
    const float* __restrict__ Whh, const float* __restrict__ bias,
    const float* __restrict__ Wout, const float* __restrict__ bout,
    float* __restrict__ out, unsigned* hbuf32)
{
  const int tid  = threadIdx.x;
  const int gb   = blockIdx.x & 15;   // batch group (16 rows)
  const int half = blockIdx.x >> 4;   // h-col half
  const int ob   = half * 128;        // own col base
  const int pb   = 128 - ob;          // peer col base
  const int wv   = tid >> 6;          // 8 waves
  const int ln   = tid & 63;
  const int g    = wv & 3;            // gate (i,f,g,o)
  const int q    = wv >> 2;           // col quarter within own half
  const int colB = ln & 15;           // MFMA n (B) / m (A) lane index
  const int krow = ln >> 4;           // MFMA k-quad

  __shared__ unsigned short h_s[16 * 264];  // full h (both halves), pitch 264
  __shared__ unsigned short x_s[16 * 72];
  __shared__ float gbuf[4 * 16 * 132];      // [gate][row][128 own cols + pad]

  // ---- W fragments: 4 tiles of gate g over own cols (B-operand layout) ----
  short8 bhw[4][8], bxw[4][2];
  float bvw[4];
  #pragma unroll
  for (int jt = 0; jt < 4; ++jt) {
    const int jr = g * H_ + ob + (q * 4 + jt) * 16 + colB;   // row in [0,4H)
    #pragma unroll
    for (int k = 0; k < 8; ++k) {
      const int kcm = (half * 4 + k) & 7;   // slot k <-> h-chunk kcm
      const float* p = Whh + jr * H_ + kcm * 32 + krow * 8;
      short8 f;
      #pragma unroll
      for (int i = 0; i < 8; ++i) f[i] = (short)f2bf(p[i]);
      bhw[jt][k] = f;
    }
    #pragma unroll
    for (int kc = 0; kc < 2; ++kc) {
      const float* p = Wih + jr * DIN_ + kc * 32 + krow * 8;
      short8 f;
      #pragma unroll
      for (int i = 0; i < 8; ++i) f[i] = (short)f2bf(p[i]);
      bxw[jt][kc] = f;
    }
    bvw[jt] = bias[jr];
  }

  // ---- cell mapping: thread owns (row crow, own cols gcol..gcol+3) ----
  const int crow = tid >> 5;            // 0..15
  const int cl4  = (tid & 31) * 4;      // 0..124
  const int grow = gb * 16 + crow;
  const int gcol = ob + cl4;
  float c_val[4], h_val[4];
  #pragma unroll
  for (int i = 0; i < 4; ++i) {
    c_val[i] = c0f[grow * H_ + gcol + i];
    h_val[i] = 0.0f;
  }

  // ---- x staging: 2 floats/thread/step, prefetched one step ahead ----
  const int xr = tid >> 5, xc = (tid & 31) * 2;
  const float* xrow = xin + (gb * 16 + xr) * (T_ * DIN_) + xc;
  {
    float2 v = *(const float2*)(xrow);            // x[t=0]
    x_s[xr * 72 + xc]     = f2bf(v.x);
    x_s[xr * 72 + xc + 1] = f2bf(v.y);
  }
  float2 xcur = *(const float2*)(xrow + DIN_);    // prefetch x[t=1]

  // ---- stage full h0 (both halves) ----
  {
    const int r = tid >> 5, c8 = (tid & 31) * 8;
    float4 v0 = *(const float4*)(h0f + (gb * 16 + r) * H_ + c8);
    float4 v1 = *(const float4*)(h0f + (gb * 16 + r) * H_ + c8 + 4);
    unsigned short* qq = &h_s[r * 264 + c8];
    qq[0] = f2bf(v0.x); qq[1] = f2bf(v0.y); qq[2] = f2bf(v0.z); qq[3] = f2bf(v0.w);
    qq[4] = f2bf(v1.x); qq[5] = f2bf(v1.y); qq[6] = f2bf(v1.z); qq[7] = f2bf(v1.w);
  }

  // hbuf32[2 parity][16 gb][16 rows][256 cols] dwords
  const int pr = tid >> 5, pc = pb + (tid & 31) * 4;   // poll target (peer)
  const unsigned* ldp_base = hbuf32 + gb * 4096 + pr * 256 + pc;
  unsigned* stp_base = hbuf32 + gb * 4096 + crow * 256 + gcol;

  __syncthreads();

  for (int s = 1; s <= T_; ++s) {
    u32x4 pv;
    const unsigned* ldp = ldp_base + (((s - 1) & 1) << 16);
    if (s > 1) poll_issue(ldp, pv);   // fire; RT overlaps local MFMA below

    // ---- phase 1: x-chunks + OWN-half h-chunks (no peer data) ----
    f32x4 acc[4] = {{0.f,0.f,0.f,0.f},{0.f,0.f,0.f,0.f},
                    {0.f,0.f,0.f,0.f},{0.f,0.f,0.f,0.f}};
    #pragma unroll
    for (int kc = 0; kc < 2; ++kc) {
      short8 a = *(const short8*)&x_s[colB * 72 + kc * 32 + krow * 8];
      #pragma unroll
      for (int jt = 0; jt < 4; ++jt)
        acc[jt] = __builtin_amdgcn_mfma_f32_16x16x32_bf16(a, bxw[jt][kc], acc[jt], 0, 0, 0);
    }
    #pragma unroll
    for (int k = 0; k < 4; ++k) {     // own chunks: slots 0..3
      const int kcm = half * 4 + k;
      short8 a = *(const short8*)&h_s[colB * 264 + kcm * 32 + krow * 8];
      #pragma unroll
      for (int jt = 0; jt < 4; ++jt)
        acc[jt] = __builtin_amdgcn_mfma_f32_16x16x32_bf16(a, bhw[jt][k], acc[jt], 0, 0, 0);
    }

    // ---- complete poll of peer half h^{s-1} ----
    if (s > 1) {
      const unsigned want = (unsigned)(s - 1);
      poll_wait(pv);
      if (!tags_ok1(pv, want)) {
        int tries = 0;
        do {
          load4_sc1(ldp, pv);
          if (tags_ok1(pv, want)) break;
        } while (++tries < (1 << 18));   // hang guard (unreachable)
      }
      unsigned* q32 = (unsigned*)&h_s[pr * 264 + pc];
      q32[0] = (pv.x & 0xFFFFu) | (pv.y << 16);
      q32[1] = (pv.z & 0xFFFFu) | (pv.w << 16);
    }
    __syncthreads();   // (B) peer half staged

    // ---- phase 2: PEER-half h-chunks ----
    #pragma unroll
    for (int k = 4; k < 8; ++k) {     // peer chunks: slots 4..7
      const int kcm = (half * 4 + k) & 7;
      short8 a = *(const short8*)&h_s[colB * 264 + kcm * 32 + krow * 8];
      #pragma unroll
      for (int jt = 0; jt < 4; ++jt)
        acc[jt] = __builtin_amdgcn_mfma_f32_16x16x32_bf16(a, bhw[jt][k], acc[jt], 0, 0, 0);
    }
    #pragma unroll
    for (int jt = 0; jt < 4; ++jt) {
      const int gc0 = (q * 4 + jt) * 16 + colB;
      #pragma unroll
      for (int i = 0; i < 4; ++i)   // D layout: col=lane&15, row=krow*4+i
        gbuf[g * 2112 + (krow * 4 + i) * 132 + gc0] = acc[jt][i] + bvw[jt];
    }
    __syncthreads();   // (C) gates staged

    // ---- cell: 4 cells/thread; publish own half; write own h_s ----
    {
      const f32x4 vi = *(const f32x4*)&gbuf[0 * 2112 + crow * 132 + cl4];
      const f32x4 vf = *(const f32x4*)&gbuf[1 * 2112 + crow * 132 + cl4];
      const f32x4 vg = *(const f32x4*)&gbuf[2 * 2112 + crow * 132 + cl4];
      const f32x4 vo = *(const f32x4*)&gbuf[3 * 2112 + crow * 132 + cl4];
      unsigned short* hq = &h_s[crow * 264 + gcol];
      unsigned* st = stp_base + ((s & 1) << 16);
      #pragma unroll
      for (int i = 0; i < 4; ++i) {
        c_val[i] = sigm(vf[i]) * c_val[i] + sigm(vi[i]) * tanh_(vg[i]);
        h_val[i] = sigm(vo[i]) * tanh_(c_val[i]);
        unsigned short hb = f2bf(h_val[i]);
        hq[i] = hb;
        __hip_atomic_store(st + i, ((unsigned)s << 16) | (unsigned)hb,
                           __ATOMIC_RELAXED, __HIP_MEMORY_SCOPE_AGENT);
      }
    }
    // restage x for step s+1 (xcur == x[s]); prefetch next
    x_s[xr * 72 + xc]     = f2bf(xcur.x);
    x_s[xr * 72 + xc + 1] = f2bf(xcur.y);
    {
      const int tn = (s + 1 < T_) ? (s + 1) : (T_ - 1);
      xcur = *(const float2*)(xrow + tn * DIN_);
    }
    __syncthreads();   // (D) h_s own + x_s ready for step s+1
  }

  // ---- outputs: rnn_outputs | logits | h | c ----
  #pragma unroll
  for (int i = 0; i < 4; ++i) {
    out[grow * H_ + gcol + i]          = h_val[i];   // out0: rnn_outputs
    out[67584 + grow * H_ + gcol + i]  = h_val[i];   // out2: h (65536+2048)
    out[133120 + grow * H_ + gcol + i] = c_val[i];   // out3: c
  }

  // ---- tail: acquire peer h^T, then logits (half==0 writes) ----
  {
    const unsigned want = (unsigned)T_;
    const unsigned* ldp = ldp_base + ((T_ & 1) << 16);
    u32x4 pv;
    int tries = 0;
    do {
      load4_sc1(ldp, pv);
      if (tags_ok1(pv, want)) break;
    } while (++tries < (1 << 18));
    unsigned* q32 = (unsigned*)&h_s[pr * 264 + pc];
    q32[0] = (pv.x & 0xFFFFu) | (pv.y << 16);
    q32[1] = (pv.z & 0xFFFFu) | (pv.w << 16);
    __syncthreads();
    if (half == 0 && tid < 128) {
      int r = tid >> 3, o = tid & 7;
      float a = bout[o];
      for (int k = 0; k < H_; ++k)
        a = fmaf(bf2f(h_s[r * 264 + k]), Wout[o * H_ + k], a);
      out[65536 + (gb * 16 + r) * 8 + o] = a;        // out1: logits
    }
  }
}

extern "C" void kernel_launch(void* const* d_in, const int* in_sizes, int n_in,
                              void* d_out, int out_size, void* d_ws, size_t ws_size,
                              hipStream_t stream) {
  const float* xin  = (const float*)d_in[0];
  const float* h0f  = (const float*)d_in[1];
  const float* c0f  = (const float*)d_in[2];
  const float* Wih  = (const float*)d_in[3];
  const float* Whh  = (const float*)d_in[4];
  const float* bias = (const float*)d_in[5];
  const float* Wout = (const float*)d_in[6];
  const float* bout = (const float*)d_in[7];
  float* out = (float*)d_out;

  // ws: hbuf32[2][16][16][256] dwords (512 KiB)
  unsigned* hbuf32 = (unsigned*)d_ws;

  void* args[] = {&xin, &h0f, &c0f, &Wih, &Whh, &bias, &Wout, &bout,
                  &out, &hbuf32};
  hipLaunchCooperativeKernel((void*)lstm_kern, dim3(32), dim3(512),
                             args, 0, stream);
}

// Round 14
// 1419.073 us; speedup vs baseline: 1.0113x; 1.0076x over previous
//
#include <hip/hip_runtime.h>

#define T_ 512
#define B_ 256
#define H_ 256
#define DIN_ 64

typedef __attribute__((ext_vector_type(8))) short short8;
typedef __attribute__((ext_vector_type(4))) float f32x4;
typedef __attribute__((ext_vector_type(4))) unsigned int u32x4;

__device__ __forceinline__ unsigned short f2bf(float f) {
  unsigned u = __float_as_uint(f);
  u += 0x7FFFu + ((u >> 16) & 1u);   // RNE
  return (unsigned short)(u >> 16);
}
__device__ __forceinline__ float bf2f(unsigned short s) {
  return __uint_as_float(((unsigned)s) << 16);
}
__device__ __forceinline__ float sigm(float x) { return 1.0f / (1.0f + __expf(-x)); }
__device__ __forceinline__ float tanh_(float x) {
  float xx = fminf(fmaxf(x, -30.0f), 30.0f);
  float e = __expf(2.0f * xx);
  return (e - 1.0f) / (e + 1.0f);
}

// sc1 (agent scope) 4x dwordx4: bypasses L1/non-agent-coherent L2 -> LLC-
// fresh. Proven instruction class (R0/R4). issue-only variant: fire the 4
// loads, no wait -- pairs with wait4more (vmcnt(4)) for pipelined polling.
__device__ __forceinline__ void issue16_sc1(const unsigned* p, u32x4& a,
                                            u32x4& b, u32x4& c, u32x4& d) {
  asm volatile(
      "global_load_dwordx4 %0, %4, off sc1\n\t"
      "global_load_dwordx4 %1, %4, off offset:16 sc1\n\t"
      "global_load_dwordx4 %2, %4, off offset:32 sc1\n\t"
      "global_load_dwordx4 %3, %4, off offset:48 sc1"
      : "=&v"(a), "=&v"(b), "=&v"(c), "=&v"(d)
      : "v"(p) : "memory");
}
// Wait until <=4 vmem ops outstanding. vmcnt retires in ISSUE order, so the
// older of the two in-flight sets is complete here.
__device__ __forceinline__ void wait4more(u32x4& a, u32x4& b, u32x4& c,
                                          u32x4& d) {
  asm volatile("s_waitcnt vmcnt(4)"
               : "+v"(a), "+v"(b), "+v"(c), "+v"(d) :: "memory");
}
// R13 BUGFIX: drain ALL in-flight poll loads while keeping BOTH sets'
// registers live ("+v" on all 8 quads). R13 let abandoned in-flight loads
// outlive their asm statement; the compiler (blind to inline-asm waitcnt
// state) reallocated those dead-looking VGPRs, and the landing loads
// clobbered them (new 0.107 fingerprint). With this drain, no poll load is
// ever outstanding when its register becomes dead. Happy-path cost ~0 (set
// B lands a few cycles after set A).
__device__ __forceinline__ void drain8(u32x4& a0, u32x4& a1, u32x4& a2,
                                       u32x4& a3, u32x4& b0, u32x4& b1,
                                       u32x4& b2, u32x4& b3) {
  asm volatile("s_waitcnt vmcnt(0)"
               : "+v"(a0), "+v"(a1), "+v"(a2), "+v"(a3),
                 "+v"(b0), "+v"(b1), "+v"(b2), "+v"(b3) :: "memory");
}
// single-shot load+wait (logits tail path)
__device__ __forceinline__ void load16_sc1(const unsigned* p, u32x4& a,
                                           u32x4& b, u32x4& c, u32x4& d) {
  asm volatile(
      "global_load_dwordx4 %0, %4, off sc1\n\t"
      "global_load_dwordx4 %1, %4, off offset:16 sc1\n\t"
      "global_load_dwordx4 %2, %4, off offset:32 sc1\n\t"
      "global_load_dwordx4 %3, %4, off offset:48 sc1\n\t"
      "s_waitcnt vmcnt(0)"
      : "=&v"(a), "=&v"(b), "=&v"(c), "=&v"(d)
      : "v"(p) : "memory");
}

__device__ __forceinline__ bool tags_ok(u32x4 a, u32x4 b, u32x4 c, u32x4 d,
                                        unsigned w) {
  unsigned m = (a.x >> 16) ^ w; m |= (a.y >> 16) ^ w;
  m |= (a.z >> 16) ^ w;         m |= (a.w >> 16) ^ w;
  m |= (b.x >> 16) ^ w;         m |= (b.y >> 16) ^ w;
  m |= (b.z >> 16) ^ w;         m |= (b.w >> 16) ^ w;
  m |= (c.x >> 16) ^ w;         m |= (c.y >> 16) ^ w;
  m |= (c.z >> 16) ^ w;         m |= (c.w >> 16) ^ w;
  m |= (d.x >> 16) ^ w;         m |= (d.y >> 16) ^ w;
  m |= (d.z >> 16) ^ w;         m |= (d.w >> 16) ^ w;
  return m == 0;
}

__device__ __forceinline__ void unpack16(unsigned* q32, u32x4 a, u32x4 b,
                                         u32x4 c, u32x4 d) {
  q32[0] = (a.x & 0xFFFFu) | (a.y << 16);
  q32[1] = (a.z & 0xFFFFu) | (a.w << 16);
  q32[2] = (b.x & 0xFFFFu) | (b.y << 16);
  q32[3] = (b.z & 0xFFFFu) | (b.w << 16);
  q32[4] = (c.x & 0xFFFFu) | (c.y << 16);
  q32[5] = (c.z & 0xFFFFu) | (c.w << 16);
  q32[6] = (d.x & 0xFFFFu) | (d.y << 16);
  q32[7] = (d.z & 0xFFFFu) | (d.w << 16);
}

// Grid: 256 wgs x 256 threads. wg = gb*16 + gc. Wave w computes gate type w
// as one 16x16 MFMA tile; W fragments VGPR-resident (40 VGPR; large-W/AGPR
// space CLOSED per R1-R3/R11).
//
// R14 = PROVEN R4 + pipelined double-poll, with the R13 register-lifetime
// race closed: breaks only select the winning set; drain8 (vmcnt(0), all 8
// quads "+v") retires every in-flight load BEFORE any register can die;
// unpack follows the drain. Protocol semantics identical to R4.
//
// h exchange element = (step_tag << 16) | bf16(h); parity double-buffered.
// Safety: wg X stores tag s+1 (clobbering its s-1 entry) only after X
// acquired ALL of s; each peer published s only after fully acquiring s-1;
// so every reader of the s-1 entry finished before the clobber. The load IS
// the poll; stores are fire-and-forget. ws re-poisoned to 0xAA each launch
// -> initial tag 0xAAAA never matches.
__global__ __launch_bounds__(256) void lstm_kern(
    const float* __restrict__ xin, const float* __restrict__ h0f,
    const float* __restrict__ c0f, const float* __restrict__ Wih,
    const float* __restrict__ Whh, const float* __restrict__ bias,
    const float* __restrict__ Wout, const float* __restrict__ bout,
    float* __restrict__ out, unsigned* hbuf32)
{
  const int tid = threadIdx.x;
  const int gb  = blockIdx.x >> 4;
  const int gc  = blockIdx.x & 15;
  const int wv  = tid >> 6;   // wave = gate type (i,f,g,o)
  const int ln  = tid & 63;
  const int colB = ln & 15;   // MFMA n / A-row m
  const int krow = ln >> 4;   // MFMA k-quad

  __shared__ unsigned short h_s[16 * 264];  // 16 rows x 256 bf16, pitch 264
  __shared__ unsigned short x_s[16 * 72];   // 16 rows x 64  bf16, pitch 72
  __shared__ float gbuf[4 * 16 * 17];       // [gate][row][col] padded

  // ---- load W fragments (B-operand layout: lane holds W[j][k=krow*8+i]) ----
  const int j = wv * H_ + gc * 16 + colB;   // row in [0,4H)
  short8 bh[8], bx[2];
  #pragma unroll
  for (int kc = 0; kc < 8; ++kc) {
    const float* p = Whh + j * H_ + kc * 32 + krow * 8;
    short8 f;
    #pragma unroll
    for (int i = 0; i < 8; ++i) f[i] = (short)f2bf(p[i]);
    bh[kc] = f;
  }
  #pragma unroll
  for (int kc = 0; kc < 2; ++kc) {
    const float* p = Wih + j * DIN_ + kc * 32 + krow * 8;
    short8 f;
    #pragma unroll
    for (int i = 0; i < 8; ++i) f[i] = (short)f2bf(p[i]);
    bx[kc] = f;
  }
  const float bval = bias[j];

  // elementwise mapping: thread owns (row er, h-col ec) of this wg's slice
  const int er = tid >> 4, ec = tid & 15;
  const int grow = gb * 16 + er;
  float c_val = c0f[grow * H_ + gc * 16 + ec];
  float h_val = 0.0f;

  // ---- x prefetch: one float4/thread, ONE STEP AHEAD ----
  const int xr = tid >> 4, xd = (tid & 15) * 4;
  const float* xrow = xin + (gb * 16 + xr) * (T_ * DIN_) + xd;
  float4 xcur = *(const float4*)(xrow);     // x for s=1 (t=0)

  // hbuf32[2 parity][16 groups][16 rows][256 cols] dwords
  const int hr = tid >> 4;            // consumer row
  const int hcb = (tid & 15) * 16;    // consumer col base (16 dwords)
  const unsigned* ldp_base = hbuf32 + gb * 4096 + hr * 256 + hcb;
  unsigned* stp_base = hbuf32 + gb * 4096 + er * 256 + gc * 16 + ec;

  for (int s = 1; s <= T_; ++s) {
    // ---- stage x_{s-1} from prefetch reg; issue next load before the poll ----
    {
      unsigned short* q = &x_s[xr * 72 + xd];
      q[0] = f2bf(xcur.x); q[1] = f2bf(xcur.y);
      q[2] = f2bf(xcur.z); q[3] = f2bf(xcur.w);
      const int tn = (s < T_) ? s : (T_ - 1);   // clamped tail load, unused
      xcur = *(const float4*)(xrow + tn * DIN_);
    }

    // ---- acquire h^(s-1): pipelined double-poll (the load IS the poll) ----
    if (s == 1) {
      #pragma unroll
      for (int it = 0; it < 4; ++it) {
        int e4 = tid + it * 256;
        int r = e4 >> 6, c4 = e4 & 63;
        const float4* p = (const float4*)(h0f + (gb * 16 + r) * H_) + c4;
        float4 v = *p;
        unsigned short* q = &h_s[r * 264 + c4 * 4];
        q[0] = f2bf(v.x); q[1] = f2bf(v.y); q[2] = f2bf(v.z); q[3] = f2bf(v.w);
      }
    } else {
      const unsigned want = (unsigned)(s - 1);
      const unsigned* ldp = ldp_base + (((s - 1) & 1) << 16);  // parity buffer
      unsigned* q32 = (unsigned*)&h_s[hr * 264 + hcb];
      u32x4 a0, a1, a2, a3, b0, b1, b2, b3;
      issue16_sc1(ldp, a0, a1, a2, a3);
      issue16_sc1(ldp, b0, b1, b2, b3);
      bool useA = true;
      int tries = 0;
      for (;;) {
        // check set A (older of the two in flight -> complete at vmcnt(4))
        wait4more(a0, a1, a2, a3);
        if (tags_ok(a0, a1, a2, a3, want)) { useA = true; break; }
        if (++tries >= (1 << 18)) { useA = true; break; }
        issue16_sc1(ldp, a0, a1, a2, a3);   // reissue A (now newest)
        // check set B (older than reissued A -> complete at vmcnt(4))
        wait4more(b0, b1, b2, b3);
        if (tags_ok(b0, b1, b2, b3, want)) { useA = false; break; }
        if (++tries >= (1 << 18)) { useA = false; break; }
        issue16_sc1(ldp, b0, b1, b2, b3);   // reissue B (now newest)
      }
      // retire ALL in-flight loads while both sets' registers are still
      // live -- only then is any of these registers allowed to die.
      drain8(a0, a1, a2, a3, b0, b1, b2, b3);
      if (useA) unpack16(q32, a0, a1, a2, a3);
      else      unpack16(q32, b0, b1, b2, b3);
    }
    __syncthreads();   // (B) x_s + h_s staged

    // ---- gates tile: D[batch m][gate col n], K = 64 (x) + 256 (h) ----
    f32x4 acc = {0.f, 0.f, 0.f, 0.f};
    #pragma unroll
    for (int kc = 0; kc < 2; ++kc) {
      short8 a = *(const short8*)&x_s[colB * 72 + kc * 32 + krow * 8];
      acc = __builtin_amdgcn_mfma_f32_16x16x32_bf16(a, bx[kc], acc, 0, 0, 0);
    }
    #pragma unroll
    for (int kc = 0; kc < 8; ++kc) {
      short8 a = *(const short8*)&h_s[colB * 264 + kc * 32 + krow * 8];
      acc = __builtin_amdgcn_mfma_f32_16x16x32_bf16(a, bh[kc], acc, 0, 0, 0);
    }
    #pragma unroll
    for (int i = 0; i < 4; ++i)   // D layout: col=lane&15, row=quad*4+i
      gbuf[wv * 272 + (krow * 4 + i) * 17 + colB] = acc[i] + bval;
    __syncthreads();   // (C)

    // ---- elementwise LSTM cell update ----
    float gi = gbuf[0 * 272 + er * 17 + ec];
    float gf = gbuf[1 * 272 + er * 17 + ec];
    float gg = gbuf[2 * 272 + er * 17 + ec];
    float go = gbuf[3 * 272 + er * 17 + ec];
    c_val = sigm(gf) * c_val + sigm(gi) * tanh_(gg);
    h_val = sigm(go) * tanh_(c_val);

    // ---- publish: fire-and-forget tagged sc1 store into parity buffer ----
    unsigned pk = ((unsigned)s << 16) | (unsigned)f2bf(h_val);
    __hip_atomic_store(stp_base + ((s & 1) << 16), pk,
                       __ATOMIC_RELAXED, __HIP_MEMORY_SCOPE_AGENT);
  }

  // ---- outputs: rnn_outputs | logits | h | c ----
  const int gj = gc * 16 + ec;
  out[grow * H_ + gj] = h_val;                 // out0: rnn_outputs
  out[67584 + grow * H_ + gj] = h_val;         // out2: h   (65536+2048)
  out[133120 + grow * H_ + gj] = c_val;        // out3: c

  if (gc == 0) {  // logits for this batch group: need full h^T rows
    const unsigned want = (unsigned)T_;
    const unsigned* ldp = ldp_base + ((T_ & 1) << 16);
    u32x4 va, vb, vc, vd;
    int tries = 0;
    do {
      load16_sc1(ldp, va, vb, vc, vd);
      if (tags_ok(va, vb, vc, vd, want)) break;
    } while (++tries < (1 << 18));
    unsigned* q32 = (unsigned*)&h_s[hr * 264 + hcb];
    unpack16(q32, va, vb, vc, vd);
    __syncthreads();
    if (tid < 128) {
      int r = tid >> 3, o = tid & 7;
      float a = bout[o];
      for (int k = 0; k < H_; ++k)
        a = fmaf(bf2f(h_s[r * 264 + k]), Wout[o * H_ + k], a);
      out[65536 + (gb * 16 + r) * 8 + o] = a;   // out1: logits
    }
  }
}

extern "C" void kernel_launch(void* const* d_in, const int* in_sizes, int n_in,
                              void* d_out, int out_size, void* d_ws, size_t ws_size,
                              hipStream_t stream) {
  const float* xin  = (const float*)d_in[0];
  const float* h0f  = (const float*)d_in[1];
  const float* c0f  = (const float*)d_in[2];
  const float* Wih  = (const float*)d_in[3];
  const float* Whh  = (const float*)d_in[4];
  const float* bias = (const float*)d_in[5];
  const float* Wout = (const float*)d_in[6];
  const float* bout = (const float*)d_in[7];
  float* out = (float*)d_out;

  // ws: hbuf32[2][16][16][256] dwords (512 KiB)
  unsigned* hbuf32 = (unsigned*)d_ws;

  void* args[] = {&xin, &h0f, &c0f, &Wih, &Whh, &bias, &Wout, &bout,
                  &out, &hbuf32};
  hipLaunchCooperativeKernel((void*)lstm_kern, dim3(256), dim3(256),
                             args, 0, stream);
}